// Round 5
// baseline (319.060 us; speedup 1.0000x reference)
//
#include <hip/hip_runtime.h>
#include <hip/hip_bf16.h>
#include <stdint.h>

constexpr int BB  = 64;    // batch
constexpr int SS  = 512;   // seq len
constexpr int HH  = 768;   // hidden
constexpr int NL  = 9;     // labels
constexpr int NROWS = BB * SS;          // 32768
constexpr int EMN   = SS * NL;          // 4608 emissions per batch
constexpr int NSEG  = 8;                // time segments for parallel lognorm
constexpr float NEG  = -1e30f;

__device__ __forceinline__ float readlane_f(float v, int lane) {
  union { float f; int i; } u;
  u.f = v;
  u.i = __builtin_amdgcn_readlane(u.i, lane);
  return u.f;
}

// 3-input max, single instruction, depth-2 trees for 9-way max.
// EXACT: float max is associative/commutative for finite inputs (no rounding).
__device__ __forceinline__ float max3f(float a, float b, float c) {
  float d;
  asm("v_max3_f32 %0, %1, %2, %3" : "=v"(d) : "v"(a), "v"(b), "v"(c));
  return d;
}

__device__ __forceinline__ float max9f(const float* c) {
  return max3f(max3f(c[0], c[1], c[2]),
               max3f(c[3], c[4], c[5]),
               max3f(c[6], c[7], c[8]));
}

// ---------------------------------------------------------------------------
// Kernel 1: logits[b,s,l] = hidden[b,s,:] @ W[:,l] + bias[l]
// Register-blocking fix vs previous rounds: W is reloaded per j-slice
// (36 regs live instead of 108), h loaded per (r,j) (16 regs instead of 48).
// Same accumulation expression/order -> bit-identical results; VGPR drops
// from ~210 to ~110-120 so occupancy rises 2 -> 4+ waves/SIMD (memory-bound
// kernel needs the TLP). Blocks 0..63 compute lens[b]; block 0 zeroes the
// loss accumulator; block 1 zeroes the combine arrival counters.
// ---------------------------------------------------------------------------
__global__ __launch_bounds__(256, 4) void logits_kernel(
    const float* __restrict__ hidden, const float* __restrict__ W,
    const float* __restrict__ bias, const int* __restrict__ mask,
    float* __restrict__ logits, int* __restrict__ lens,
    float* __restrict__ out, int* __restrict__ cnt) {
  const int lane = threadIdx.x & 63;
  const int wid  = blockIdx.x * 4 + (threadIdx.x >> 6);   // 8192 waves

  if (blockIdx.x == 0 && threadIdx.x == 0) out[0] = 0.0f;
  if (blockIdx.x == 1 && threadIdx.x < BB) cnt[threadIdx.x] = 0;

  if (blockIdx.x < 64 && threadIdx.x < 64) {
    const int4* mp = (const int4*)(mask + blockIdx.x * SS);
    const int4 a = mp[threadIdx.x];
    const int4 c = mp[threadIdx.x + 64];
    int lsum = a.x + a.y + a.z + a.w + c.x + c.y + c.z + c.w;
#pragma unroll
    for (int off = 32; off >= 1; off >>= 1) lsum += __shfl_xor(lsum, off, 64);
    if (threadIdx.x == 0) lens[blockIdx.x] = lsum;
  }

  const float my_bias = (lane < NL) ? bias[lane] : 0.0f;

  const float4* hp[4];
#pragma unroll
  for (int r = 0; r < 4; ++r)
    hp[r] = (const float4*)(hidden + (size_t)(wid + r * 8192) * HH);

  float acc[4][NL];
#pragma unroll
  for (int r = 0; r < 4; ++r)
#pragma unroll
    for (int l = 0; l < NL; ++l) acc[r][l] = 0.0f;

#pragma unroll
  for (int j = 0; j < 3; ++j) {
    float w[4][NL];                      // only this j-slice of W lives
#pragma unroll
    for (int k = 0; k < 4; ++k) {
      const int r = lane * 4 + j * 256 + k;
#pragma unroll
      for (int l = 0; l < NL; ++l) w[k][l] = W[r * NL + l];
    }
#pragma unroll
    for (int r = 0; r < 4; ++r) {
      const float4 h = hp[r][lane + j * 64];
#pragma unroll
      for (int l = 0; l < NL; ++l)
        acc[r][l] += h.x * w[0][l] + h.y * w[1][l] +
                     h.z * w[2][l] + h.w * w[3][l];
    }
  }
#pragma unroll
  for (int off = 32; off >= 1; off >>= 1)
#pragma unroll
    for (int r = 0; r < 4; ++r)
#pragma unroll
      for (int l = 0; l < NL; ++l)
        acc[r][l] += __shfl_xor(acc[r][l], off, 64);
  if (lane < NL) {
#pragma unroll
    for (int r = 0; r < 4; ++r) {
      float v = acc[r][0];
#pragma unroll
      for (int l = 1; l < NL; ++l) if (lane == l) v = acc[r][l];
      logits[(size_t)(wid + r * 8192) * NL + lane] = v + my_bias;
    }
  }
}

// combine logic, run by the LAST arriving producer block of each batch.
// Bit-identical arithmetic to the original combine_kernel.
__device__ void combine_batch(int b, int tid,
                              const float* __restrict__ logits,
                              const float* __restrict__ segmat,
                              const float* __restrict__ start_t,
                              const float* __restrict__ end_t,
                              const float* __restrict__ num_den,
                              float* __restrict__ out) {
  const int j = (tid < NL) ? tid : NL - 1;
  float s[NL];
#pragma unroll
  for (int i = 0; i < NL; ++i) s[i] = start_t[i] + logits[(size_t)b * EMN + i];
  float mcur[NL], mnxt[NL];
  {
    const float* M = segmat + (size_t)(b * NSEG) * 81;
#pragma unroll
    for (int i = 0; i < NL; ++i) mcur[i] = M[i * NL + j];
  }
  for (int sg = 0; sg < NSEG; ++sg) {
    if (sg + 1 < NSEG) {
      const float* M = segmat + (size_t)(b * NSEG + sg + 1) * 81;
#pragma unroll
      for (int i = 0; i < NL; ++i) mnxt[i] = M[i * NL + j];
    }
    float c[NL];
#pragma unroll
    for (int i = 0; i < NL; ++i) c[i] = s[i] + mcur[i];
    const float m = max9f(c);
    float sum = 0.0f;
#pragma unroll
    for (int i = 0; i < NL; ++i) sum += __expf(c[i] - m);
    const float nxt = m + __logf(sum);
#pragma unroll
    for (int i = 0; i < NL; ++i) s[i] = readlane_f(nxt, i);
#pragma unroll
    for (int i = 0; i < NL; ++i) mcur[i] = mnxt[i];
  }
  float c[NL];
#pragma unroll
  for (int i = 0; i < NL; ++i) c[i] = s[i] + end_t[i];
  const float m = max9f(c);
  float sum = 0.0f;
#pragma unroll
  for (int i = 0; i < NL; ++i) sum += __expf(c[i] - m);
  if (tid == 0) {
    const float den = m + __logf(sum);
    atomicAdd(out, (den - num_den[b]) * (1.0f / 64.0f));
  }
}

// ---------------------------------------------------------------------------
// Kernel 2: rest_kernel — 1600 one-wave blocks, NO viterbi (split out so the
// serial chain can later run with the machine to itself).
//   blk  0..  63 : numerator (gold-path score), parallel over t
//   blk 64..1599 : lognorm segment scans, 3 basis chains per wave (ILP-3)
// Last arriving producer block per batch (25 total) runs combine.
// ---------------------------------------------------------------------------
__global__ __launch_bounds__(64) void rest_kernel(
    const float* __restrict__ logits, const int* __restrict__ labels,
    const float* __restrict__ start_t, const float* __restrict__ end_t,
    const float* __restrict__ trans, float* __restrict__ out,
    float* __restrict__ num_den, const int* __restrict__ lens,
    float* __restrict__ segmat, int* __restrict__ cnt) {
  __shared__ unsigned char lab[SS];

  const int blk = blockIdx.x;
  const int tid = threadIdx.x;
  const int j   = (tid < NL) ? tid : NL - 1;

  if (blk < 64) {
    // ================= numerator =================
    const int b   = blk;
    const int len = lens[b];
    const float* emb = logits + (size_t)b * EMN;
    for (int t = tid; t < SS; t += 64) {
      const int v = labels[b * SS + t];
      lab[t] = (unsigned char)((v == -100) ? 0 : v);
    }
    __syncthreads();
    float contrib = 0.0f;
    for (int t = tid; t < SS; t += 64) {
      if (t >= 1 && t < len)
        contrib += emb[t * NL + lab[t]] + trans[lab[t - 1] * NL + lab[t]];
    }
#pragma unroll
    for (int off = 32; off >= 1; off >>= 1)
      contrib += __shfl_xor(contrib, off, 64);
    if (tid == 0) {
      const int l0 = lab[0];
      num_den[b] = start_t[l0] + emb[l0] + contrib + end_t[lab[len - 1]];
    }
    __threadfence();
    int old = 0;
    if (tid == 0) old = atomicAdd(&cnt[b], 1);
    old = __builtin_amdgcn_readlane(old, 0);
    if (old == 24) {
      __threadfence();
      combine_batch(b, tid, logits, segmat, start_t, end_t, num_den, out);
    }

  } else {
    // ================= lognorm segment scan, 3 chains per wave =================
    const int id   = blk - 64;         // 0..1535
    const int pair = id / 3;           // (b, sg)
    const int wv   = id - pair * 3;    // which e-triple
    const int b    = pair >> 3;
    const int sg   = pair & 7;
    const int e0   = 3 * wv;           // chains e0, e0+1, e0+2
    const int len  = lens[b];
    const float* emb = logits + (size_t)b * EMN;
    float tc[NL];
#pragma unroll
    for (int i = 0; i < NL; ++i) tc[i] = trans[i * NL + j];
    float s0[NL], s1[NL], s2[NL];
#pragma unroll
    for (int i = 0; i < NL; ++i) {
      s0[i] = (i == e0)     ? 0.0f : NEG;
      s1[i] = (i == e0 + 1) ? 0.0f : NEG;
      s2[i] = (i == e0 + 2) ? 0.0f : NEG;
    }
    float my0 = (j == e0)     ? 0.0f : NEG;
    float my1 = (j == e0 + 1) ? 0.0f : NEG;
    float my2 = (j == e0 + 2) ? 0.0f : NEG;
    const int tbeg  = 64 * sg + 1;
    const int tlast = (64 * sg + 64 < 511) ? 64 * sg + 64 : 511;
    float eA = emb[tbeg * NL + j],       eB = emb[(tbeg + 1) * NL + j];
    float eC = emb[(tbeg + 2) * NL + j], eD = emb[(tbeg + 3) * NL + j];
    for (int t = tbeg; t <= tlast; ++t) {
      if (t >= len) break;             // prefix mask: rest are identity steps
      float c0[NL], c1[NL], c2[NL];
#pragma unroll
      for (int i = 0; i < NL; ++i) {
        c0[i] = s0[i] + tc[i];
        c1[i] = s1[i] + tc[i];
        c2[i] = s2[i] + tc[i];
      }
      const float m0 = max9f(c0);
      const float m1 = max9f(c1);
      const float m2 = max9f(c2);
      float u0 = 0.0f, u1 = 0.0f, u2 = 0.0f;
#pragma unroll
      for (int i = 0; i < NL; ++i) {
        u0 += __expf(c0[i] - m0);
        u1 += __expf(c1[i] - m1);
        u2 += __expf(c2[i] - m2);
      }
      my0 = m0 + __logf(u0) + eA;
      my1 = m1 + __logf(u1) + eA;
      my2 = m2 + __logf(u2) + eA;
#pragma unroll
      for (int i = 0; i < NL; ++i) {
        s0[i] = readlane_f(my0, i);
        s1[i] = readlane_f(my1, i);
        s2[i] = readlane_f(my2, i);
      }
      eA = eB; eB = eC; eC = eD;
      eD = emb[(t + 4) * NL + j];
    }
    if (tid < NL) {
      float* M = segmat + (size_t)(b * NSEG + sg) * 81;
      M[(e0    ) * NL + tid] = my0;
      M[(e0 + 1) * NL + tid] = my1;
      M[(e0 + 2) * NL + tid] = my2;
    }
    __threadfence();
    int old = 0;
    if (tid == 0) old = atomicAdd(&cnt[b], 1);
    old = __builtin_amdgcn_readlane(old, 0);
    if (old == 24) {
      __threadfence();
      combine_batch(b, tid, logits, segmat, start_t, end_t, num_den, out);
    }
  }
}

// ---------------------------------------------------------------------------
// Kernel 3: viterbi — 64 one-wave blocks, launched LAST so each wave has an
// entire CU (and SIMD issue port) to itself: tests/removes the co-residency
// arbitration stall. Round-3 proven structure: argmax in-loop, backpointers
// nibble-packed (one predicated ds_write_b32 per 8 steps), emissions
// double-buffered in registers.
// ---------------------------------------------------------------------------
__global__ __launch_bounds__(64) void viterbi_kernel(
    const float* __restrict__ logits, const float* __restrict__ start_t,
    const float* __restrict__ end_t, const float* __restrict__ trans,
    float* __restrict__ out, const int* __restrict__ lens) {
  __shared__ uint32_t bpw[64 * NL];             // packed backpointers: 2304 B
  __shared__ unsigned char tags_s[SS];

  const int tid = threadIdx.x;
  const int j   = (tid < NL) ? tid : NL - 1;

  __builtin_amdgcn_s_setprio(1);
  const int b   = blockIdx.x;
  const int len = lens[b];
  const float* emb = logits + (size_t)b * EMN;

  float tc[NL];
#pragma unroll
  for (int i = 0; i < NL; ++i) tc[i] = trans[i * NL + j];
  float s[NL];
#pragma unroll
  for (int i = 0; i < NL; ++i) s[i] = start_t[i] + emb[i];

  // double-buffered emission registers: block tb covers t = 8*tb+1 .. 8*tb+8
  float e0[8], e1[8];
#pragma unroll
  for (int k = 0; k < 8; ++k) e0[k] = emb[(1 + k) * NL + j];

  for (int tb = 0; tb < 64; ++tb) {
    const int tbase = 8 * tb;
    if (tbase + 1 >= len) break;
    if (tb < 63) {
      // prefetch next block's emissions (tb==62 reads 9 floats past this
      // batch's logits into the next batch's region / segmat -- harmless,
      // never consumed since t=512 >= len always).
#pragma unroll
      for (int k = 0; k < 8; ++k) e1[k] = emb[(tbase + 9 + k) * NL + j];
    }
    uint32_t wpk = 0;
#pragma unroll
    for (int k = 0; k < 8; ++k) {
      const int t = tbase + 1 + k;
      if (t < len) {                           // wave-uniform (len in SGPR)
        float c[NL];
#pragma unroll
        for (int i = 0; i < NL; ++i) c[i] = s[i] + tc[i];
        // CRITICAL PATH: value max via depth-2 max3 (exact reassociation)
        const float best = max9f(c);
        const float nxt  = best + e0[k];
        // OFF-PATH: argmax select tree (ref tie-breaking: lowest idx)
        {
          const bool b01 = c[0] >= c[1], b23 = c[2] >= c[3];
          const bool b45 = c[4] >= c[5], b67 = c[6] >= c[7];
          const float v01 = b01 ? c[0] : c[1]; const int i01 = b01 ? 0 : 1;
          const float v23 = b23 ? c[2] : c[3]; const int i23 = b23 ? 2 : 3;
          const float v45 = b45 ? c[4] : c[5]; const int i45 = b45 ? 4 : 5;
          const float v67 = b67 ? c[6] : c[7]; const int i67 = b67 ? 6 : 7;
          const bool bA = v01 >= v23, bB = v45 >= v67;
          const float vA = bA ? v01 : v23; const int iA = bA ? i01 : i23;
          const float vB = bB ? v45 : v67; const int iB = bB ? i45 : i67;
          const bool bC = vA >= vB;
          const float vC = bC ? vA : vB; const int iC = bC ? iA : iB;
          const bool bD = vC >= c[8];
          const int arg = bD ? iC : 8;
          wpk |= (uint32_t)arg << (4 * k);
        }
#pragma unroll
        for (int i = 0; i < NL; ++i) s[i] = readlane_f(nxt, i);
      }
    }
    if (tid < NL) bpw[tb * NL + tid] = wpk;
#pragma unroll
    for (int k = 0; k < 8; ++k) e0[k] = e1[k];
  }
  float bv = s[0] + end_t[0];
  int   bl = 0;
#pragma unroll
  for (int i = 1; i < NL; ++i) {
    const float cc = s[i] + end_t[i];
    if (cc > bv) { bv = cc; bl = i; }
  }
  __syncthreads();

  // backtrace: chunked map composition over packed backpointer words.
  // lane tid owns t = 8*tid+1 .. 8*tid+8 -> exactly word-block tb = tid.
  uint32_t wv_[NL];
#pragma unroll
  for (int x = 0; x < NL; ++x) wv_[x] = bpw[tid * NL + x];
  uint64_t C = 0x876543210ULL;
#pragma unroll
  for (int k = 1; k <= 8; ++k) {
    const int t = 8 * tid + k;
    uint64_t nc = 0;
#pragma unroll
    for (int x = 0; x < 9; ++x) {
      const int g = (int)((wv_[x] >> (4 * (k - 1))) & 15u);
      nc |= ((C >> (4 * g)) & 15ULL) << (4 * x);
    }
    C = (t < len) ? nc : C;
  }
  const uint32_t Clo = (uint32_t)C, Chi = (uint32_t)(C >> 32);
  uint32_t cur = (uint32_t)bl;
  int bnd = 0;
#pragma unroll
  for (int c = 63; c >= 0; --c) {
    bnd = (tid == c) ? (int)cur : bnd;
    const uint32_t lo = (uint32_t)__builtin_amdgcn_readlane((int)Clo, c);
    const uint32_t hi = (uint32_t)__builtin_amdgcn_readlane((int)Chi, c);
    const uint64_t cc = ((uint64_t)hi << 32) | lo;
    cur = (uint32_t)((cc >> (4 * cur)) & 15u);
  }
  int tag = bnd;
#pragma unroll
  for (int k = 8; k >= 1; --k) {
    const int t = 8 * tid + k;
    const int tt = (t < 512) ? t : 511;
    const int blk2 = (tt - 1) >> 3;            // word block holding step tt
    const int kk   = tt - 8 * blk2;            // 1..8 within block
    const uint32_t bw = bpw[blk2 * NL + tag];  // dynamic LDS read (off-path)
    const int nt = (int)((bw >> (4 * (kk - 1))) & 15u);
    tag = (t < len) ? nt : tag;
    tags_s[t - 1] = (unsigned char)tag;
  }
  __syncthreads();
  for (int i = tid; i < EMN; i += 64) {
    const int t = i / NL;
    const int l = i - t * NL;
    out[1 + (size_t)b * EMN + i] =
        (t < len && l == (int)tags_s[t]) ? 1.0f : 0.0f;
  }
}

extern "C" void kernel_launch(void* const* d_in, const int* in_sizes, int n_in,
                              void* d_out, int out_size, void* d_ws, size_t ws_size,
                              hipStream_t stream) {
  const float* hidden  = (const float*)d_in[0];
  const int*   mask    = (const int*)d_in[1];
  const int*   labels  = (const int*)d_in[2];
  const float* W       = (const float*)d_in[3];
  const float* bias    = (const float*)d_in[4];
  const float* start_t = (const float*)d_in[5];
  const float* end_t   = (const float*)d_in[6];
  const float* trans   = (const float*)d_in[7];
  float* out = (float*)d_out;

  float* logits  = (float*)d_ws;                      // 294912 floats
  float* segmat  = logits + (size_t)NROWS * NL;       // 64*8*81 floats
  float* num_den = segmat + (size_t)BB * NSEG * 81;   // 64 floats (num)
  int*   lens    = (int*)(num_den + 128);             // 64 ints
  int*   cnt     = lens + 64;                         // 64 ints (arrival)

  logits_kernel<<<2048, 256, 0, stream>>>(hidden, W, bias, mask, logits, lens,
                                          out, cnt);
  rest_kernel<<<1600, 64, 0, stream>>>(logits, labels, start_t, end_t, trans,
                                       out, num_den, lens, segmat, cnt);
  viterbi_kernel<<<64, 64, 0, stream>>>(logits, start_t, end_t, trans,
                                        out, lens);
}

// Round 6
// 250.971 us; speedup vs baseline: 1.2713x; 1.2713x over previous
//
#include <hip/hip_runtime.h>
#include <hip/hip_bf16.h>
#include <stdint.h>

constexpr int BB  = 64;    // batch
constexpr int SS  = 512;   // seq len
constexpr int HH  = 768;   // hidden
constexpr int NL  = 9;     // labels
constexpr int NROWS = BB * SS;          // 32768
constexpr int EMN   = SS * NL;          // 4608 emissions per batch
constexpr int NSEG  = 8;                // time segments for parallel lognorm
constexpr int NCH   = BB * NSEG * NL;   // 4608 lognorm basis chains
constexpr int GPW   = 7;                // chains (9-lane groups) per wave
constexpr int NLOGW = (NCH + GPW - 1) / GPW;  // 659 lognorm waves
constexpr float NEG  = -1e30f;

__device__ __forceinline__ float readlane_f(float v, int lane) {
  union { float f; int i; } u;
  u.f = v;
  u.i = __builtin_amdgcn_readlane(u.i, lane);
  return u.f;
}

// group-local gather: each lane pulls src value from lane (byte_addr/4)
__device__ __forceinline__ float bperm_f(int byte_addr, float v) {
  union { float f; int i; } u;
  u.f = v;
  u.i = __builtin_amdgcn_ds_bpermute(byte_addr, u.i);
  return u.f;
}

// 3-input max, single instruction, depth-2 trees for 9-way max.
// EXACT: float max is associative/commutative for finite inputs (no rounding).
__device__ __forceinline__ float max3f(float a, float b, float c) {
  float d;
  asm("v_max3_f32 %0, %1, %2, %3" : "=v"(d) : "v"(a), "v"(b), "v"(c));
  return d;
}

__device__ __forceinline__ float max9f(const float* c) {
  return max3f(max3f(c[0], c[1], c[2]),
               max3f(c[3], c[4], c[5]),
               max3f(c[6], c[7], c[8]));
}

// ---------------------------------------------------------------------------
// Kernel 1: logits[b,s,l] = hidden[b,s,:] @ W[:,l] + bias[l]
// Register-blocked (W reloaded per j-slice) so VGPR ~110 -> 4+ waves/SIMD.
// Blocks 0..63 compute lens[b]; block 0 zeroes loss acc; block 1 zeroes the
// combine arrival counters.
// ---------------------------------------------------------------------------
__global__ __launch_bounds__(256, 4) void logits_kernel(
    const float* __restrict__ hidden, const float* __restrict__ W,
    const float* __restrict__ bias, const int* __restrict__ mask,
    float* __restrict__ logits, int* __restrict__ lens,
    float* __restrict__ out, int* __restrict__ cnt) {
  const int lane = threadIdx.x & 63;
  const int wid  = blockIdx.x * 4 + (threadIdx.x >> 6);   // 8192 waves

  if (blockIdx.x == 0 && threadIdx.x == 0) out[0] = 0.0f;
  if (blockIdx.x == 1 && threadIdx.x < BB) cnt[threadIdx.x] = 0;

  if (blockIdx.x < 64 && threadIdx.x < 64) {
    const int4* mp = (const int4*)(mask + blockIdx.x * SS);
    const int4 a = mp[threadIdx.x];
    const int4 c = mp[threadIdx.x + 64];
    int lsum = a.x + a.y + a.z + a.w + c.x + c.y + c.z + c.w;
#pragma unroll
    for (int off = 32; off >= 1; off >>= 1) lsum += __shfl_xor(lsum, off, 64);
    if (threadIdx.x == 0) lens[blockIdx.x] = lsum;
  }

  const float my_bias = (lane < NL) ? bias[lane] : 0.0f;

  const float4* hp[4];
#pragma unroll
  for (int r = 0; r < 4; ++r)
    hp[r] = (const float4*)(hidden + (size_t)(wid + r * 8192) * HH);

  float acc[4][NL];
#pragma unroll
  for (int r = 0; r < 4; ++r)
#pragma unroll
    for (int l = 0; l < NL; ++l) acc[r][l] = 0.0f;

#pragma unroll
  for (int j = 0; j < 3; ++j) {
    float w[4][NL];                      // only this j-slice of W lives
#pragma unroll
    for (int k = 0; k < 4; ++k) {
      const int r = lane * 4 + j * 256 + k;
#pragma unroll
      for (int l = 0; l < NL; ++l) w[k][l] = W[r * NL + l];
    }
#pragma unroll
    for (int r = 0; r < 4; ++r) {
      const float4 h = hp[r][lane + j * 64];
#pragma unroll
      for (int l = 0; l < NL; ++l)
        acc[r][l] += h.x * w[0][l] + h.y * w[1][l] +
                     h.z * w[2][l] + h.w * w[3][l];
    }
  }
#pragma unroll
  for (int off = 32; off >= 1; off >>= 1)
#pragma unroll
    for (int r = 0; r < 4; ++r)
#pragma unroll
      for (int l = 0; l < NL; ++l)
        acc[r][l] += __shfl_xor(acc[r][l], off, 64);
  if (lane < NL) {
#pragma unroll
    for (int r = 0; r < 4; ++r) {
      float v = acc[r][0];
#pragma unroll
      for (int l = 1; l < NL; ++l) if (lane == l) v = acc[r][l];
      logits[(size_t)(wid + r * 8192) * NL + lane] = v + my_bias;
    }
  }
}

// combine logic, run by the LAST arriving producer of each batch (73 total:
// 72 basis chains + 1 numerator). Bit-identical to the original combine.
__device__ void combine_batch(int b, int tid,
                              const float* __restrict__ logits,
                              const float* __restrict__ segmat,
                              const float* __restrict__ start_t,
                              const float* __restrict__ end_t,
                              const float* __restrict__ num_den,
                              float* __restrict__ out) {
  const int j = (tid < NL) ? tid : NL - 1;
  float s[NL];
#pragma unroll
  for (int i = 0; i < NL; ++i) s[i] = start_t[i] + logits[(size_t)b * EMN + i];
  float mcur[NL], mnxt[NL];
  {
    const float* M = segmat + (size_t)(b * NSEG) * 81;
#pragma unroll
    for (int i = 0; i < NL; ++i) mcur[i] = M[i * NL + j];
  }
  for (int sg = 0; sg < NSEG; ++sg) {
    if (sg + 1 < NSEG) {
      const float* M = segmat + (size_t)(b * NSEG + sg + 1) * 81;
#pragma unroll
      for (int i = 0; i < NL; ++i) mnxt[i] = M[i * NL + j];
    }
    float c[NL];
#pragma unroll
    for (int i = 0; i < NL; ++i) c[i] = s[i] + mcur[i];
    const float m = max9f(c);
    float sum = 0.0f;
#pragma unroll
    for (int i = 0; i < NL; ++i) sum += __expf(c[i] - m);
    const float nxt = m + __logf(sum);
#pragma unroll
    for (int i = 0; i < NL; ++i) s[i] = readlane_f(nxt, i);
#pragma unroll
    for (int i = 0; i < NL; ++i) mcur[i] = mnxt[i];
  }
  float c[NL];
#pragma unroll
  for (int i = 0; i < NL; ++i) c[i] = s[i] + end_t[i];
  const float m = max9f(c);
  float sum = 0.0f;
#pragma unroll
  for (int i = 0; i < NL; ++i) sum += __expf(c[i] - m);
  if (tid == 0) {
    const float den = m + __logf(sum);
    atomicAdd(out, (den - num_den[b]) * (1.0f / 64.0f));
  }
}

// ---------------------------------------------------------------------------
// Kernel 2: scan kernel, 787 one-wave blocks.
//   blk   0..  63 : viterbi (round-5 proven structure, bit-exact tags)
//   blk  64.. 127 : numerator
//   blk 128.. 786 : lognorm, 7 chains per wave in 9-lane groups. Lane 9g+i
//                   holds state i of chain g; the state broadcast is 9
//                   ds_bpermute gathers. Same expression order as before ->
//                   bit-identical segmat, ~5.8x fewer instructions/chain.
//   Last arriving producer per batch runs combine in-place.
// ---------------------------------------------------------------------------
__global__ __launch_bounds__(64) void scan_kernel(
    const float* __restrict__ logits, const int* __restrict__ labels,
    const float* __restrict__ start_t, const float* __restrict__ end_t,
    const float* __restrict__ trans, float* __restrict__ out,
    float* __restrict__ num_den, const int* __restrict__ lens,
    float* __restrict__ segmat, int* __restrict__ cnt) {
  __shared__ uint32_t bpw[64 * NL];             // packed backpointers: 2304 B
  __shared__ unsigned char tags_s[SS];
  __shared__ unsigned char lab[SS];

  const int blk = blockIdx.x;
  const int tid = threadIdx.x;
  const int j   = (tid < NL) ? tid : NL - 1;

  if (blk < 64) {
    // ================= viterbi =================
    __builtin_amdgcn_s_setprio(1);
    const int b   = blk;
    const int len = lens[b];
    const float* emb = logits + (size_t)b * EMN;

    float tc[NL];
#pragma unroll
    for (int i = 0; i < NL; ++i) tc[i] = trans[i * NL + j];
    float s[NL];
#pragma unroll
    for (int i = 0; i < NL; ++i) s[i] = start_t[i] + emb[i];

    float e0[8], e1[8];
#pragma unroll
    for (int k = 0; k < 8; ++k) e0[k] = emb[(1 + k) * NL + j];

    for (int tb = 0; tb < 64; ++tb) {
      const int tbase = 8 * tb;
      if (tbase + 1 >= len) break;
      if (tb < 63) {
#pragma unroll
        for (int k = 0; k < 8; ++k) e1[k] = emb[(tbase + 9 + k) * NL + j];
      }
      uint32_t wpk = 0;
#pragma unroll
      for (int k = 0; k < 8; ++k) {
        const int t = tbase + 1 + k;
        if (t < len) {                           // wave-uniform
          float c[NL];
#pragma unroll
          for (int i = 0; i < NL; ++i) c[i] = s[i] + tc[i];
          const float best = max9f(c);           // critical path
          const float nxt  = best + e0[k];
          {                                      // off-path argmax
            const bool b01 = c[0] >= c[1], b23 = c[2] >= c[3];
            const bool b45 = c[4] >= c[5], b67 = c[6] >= c[7];
            const float v01 = b01 ? c[0] : c[1]; const int i01 = b01 ? 0 : 1;
            const float v23 = b23 ? c[2] : c[3]; const int i23 = b23 ? 2 : 3;
            const float v45 = b45 ? c[4] : c[5]; const int i45 = b45 ? 4 : 5;
            const float v67 = b67 ? c[6] : c[7]; const int i67 = b67 ? 6 : 7;
            const bool bA = v01 >= v23, bB = v45 >= v67;
            const float vA = bA ? v01 : v23; const int iA = bA ? i01 : i23;
            const float vB = bB ? v45 : v67; const int iB = bB ? i45 : i67;
            const bool bC = vA >= vB;
            const float vC = bC ? vA : vB; const int iC = bC ? iA : iB;
            const bool bD = vC >= c[8];
            const int arg = bD ? iC : 8;
            wpk |= (uint32_t)arg << (4 * k);
          }
#pragma unroll
          for (int i = 0; i < NL; ++i) s[i] = readlane_f(nxt, i);
        }
      }
      if (tid < NL) bpw[tb * NL + tid] = wpk;
#pragma unroll
      for (int k = 0; k < 8; ++k) e0[k] = e1[k];
    }
    float bv = s[0] + end_t[0];
    int   bl = 0;
#pragma unroll
    for (int i = 1; i < NL; ++i) {
      const float cc = s[i] + end_t[i];
      if (cc > bv) { bv = cc; bl = i; }
    }
    __syncthreads();

    // backtrace: chunked map composition over packed backpointer words
    uint32_t wv_[NL];
#pragma unroll
    for (int x = 0; x < NL; ++x) wv_[x] = bpw[tid * NL + x];
    uint64_t C = 0x876543210ULL;
#pragma unroll
    for (int k = 1; k <= 8; ++k) {
      const int t = 8 * tid + k;
      uint64_t nc = 0;
#pragma unroll
      for (int x = 0; x < 9; ++x) {
        const int g = (int)((wv_[x] >> (4 * (k - 1))) & 15u);
        nc |= ((C >> (4 * g)) & 15ULL) << (4 * x);
      }
      C = (t < len) ? nc : C;
    }
    const uint32_t Clo = (uint32_t)C, Chi = (uint32_t)(C >> 32);
    uint32_t cur = (uint32_t)bl;
    int bnd = 0;
#pragma unroll
    for (int c = 63; c >= 0; --c) {
      bnd = (tid == c) ? (int)cur : bnd;
      const uint32_t lo = (uint32_t)__builtin_amdgcn_readlane((int)Clo, c);
      const uint32_t hi = (uint32_t)__builtin_amdgcn_readlane((int)Chi, c);
      const uint64_t cc = ((uint64_t)hi << 32) | lo;
      cur = (uint32_t)((cc >> (4 * cur)) & 15u);
    }
    int tag = bnd;
#pragma unroll
    for (int k = 8; k >= 1; --k) {
      const int t = 8 * tid + k;
      const int tt = (t < 512) ? t : 511;
      const int blk2 = (tt - 1) >> 3;
      const int kk   = tt - 8 * blk2;
      const uint32_t bw = bpw[blk2 * NL + tag];
      const int nt = (int)((bw >> (4 * (kk - 1))) & 15u);
      tag = (t < len) ? nt : tag;
      tags_s[t - 1] = (unsigned char)tag;
    }
    __syncthreads();
    for (int i = tid; i < EMN; i += 64) {
      const int t = i / NL;
      const int l = i - t * NL;
      out[1 + (size_t)b * EMN + i] =
          (t < len && l == (int)tags_s[t]) ? 1.0f : 0.0f;
    }

  } else if (blk < 128) {
    // ================= numerator =================
    const int b   = blk - 64;
    const int len = lens[b];
    const float* emb = logits + (size_t)b * EMN;
    for (int t = tid; t < SS; t += 64) {
      const int v = labels[b * SS + t];
      lab[t] = (unsigned char)((v == -100) ? 0 : v);
    }
    __syncthreads();
    float contrib = 0.0f;
    for (int t = tid; t < SS; t += 64) {
      if (t >= 1 && t < len)
        contrib += emb[t * NL + lab[t]] + trans[lab[t - 1] * NL + lab[t]];
    }
#pragma unroll
    for (int off = 32; off >= 1; off >>= 1)
      contrib += __shfl_xor(contrib, off, 64);
    if (tid == 0) {
      const int l0 = lab[0];
      num_den[b] = start_t[l0] + emb[l0] + contrib + end_t[lab[len - 1]];
    }
    __threadfence();
    int old = -1;
    if (tid == 0) old = atomicAdd(&cnt[b], 1);
    old = __builtin_amdgcn_readlane(old, 0);
    if (old == 72) {
      __threadfence();
      combine_batch(b, tid, logits, segmat, start_t, end_t, num_den, out);
    }

  } else {
    // ============ lognorm: 7 chains per wave, 9-lane groups ============
    const int w   = blk - 128;               // 0..658
    const int g   = tid / 9;                 // 0..7 (g==7: lane 63, idle)
    const int i   = tid - 9 * g;             // state index within group
    const int cid = GPW * w + g;
    const bool valid = (g < GPW) && (cid < NCH);
    const int cc  = valid ? cid : (NCH - 1); // idle lanes duplicate last chain
    const int pr  = cc / 9;                  // (b, sg) pair
    const int e   = cc - 9 * pr;             // basis index
    const int b   = pr >> 3;
    const int sg  = pr & 7;
    const int len = lens[b];
    const int base4 = (g < GPW) ? (9 * g * 4) : 0;   // group gather base
    const float* embp = logits + (size_t)b * EMN + i;

    float tc[NL];
#pragma unroll
    for (int k = 0; k < NL; ++k) tc[k] = trans[k * NL + i];
    float my = (i == e) ? 0.0f : NEG;        // basis initial state
    const int tbeg = 64 * sg + 1;

    // rolling 4-deep emission prefetch (per-lane column i of row t).
    // max read index (64*sg+68)*9+8 for sg=7, b=63 lands in segmat: harmless.
    float eA = embp[(size_t)(tbeg    ) * NL], eB = embp[(size_t)(tbeg + 1) * NL];
    float eC = embp[(size_t)(tbeg + 2) * NL], eD = embp[(size_t)(tbeg + 3) * NL];

    for (int st = 0; st < 64; ++st) {
      const int t = tbeg + st;               // per-lane absolute time
      if (__ballot((g < GPW) && (t < len)) == 0ull) break;
      float s[NL], c[NL];
#pragma unroll
      for (int k = 0; k < NL; ++k) s[k] = bperm_f(base4 + 4 * k, my);
#pragma unroll
      for (int k = 0; k < NL; ++k) c[k] = s[k] + tc[k];
      const float m = max9f(c);
      float u = 0.0f;
#pragma unroll
      for (int k = 0; k < NL; ++k) u += __expf(c[k] - m);
      const float nv = m + __logf(u) + eA;
      my = (t < len) ? nv : my;              // reference mask semantics
      eA = eB; eB = eC; eC = eD;
      eD = embp[(size_t)(t + 4) * NL];
    }
    if (valid) segmat[(size_t)pr * 81 + e * NL + i] = my;
    __threadfence();
    int old = -1;
    if (valid && i == 0) old = atomicAdd(&cnt[b], 1);
#pragma unroll
    for (int g2 = 0; g2 < GPW; ++g2) {
      const int og = __builtin_amdgcn_readlane(old, 9 * g2);
      if (og == 72) {
        const int bg = __builtin_amdgcn_readlane(b, 9 * g2);
        __threadfence();
        combine_batch(bg, tid, logits, segmat, start_t, end_t, num_den, out);
      }
    }
  }
}

extern "C" void kernel_launch(void* const* d_in, const int* in_sizes, int n_in,
                              void* d_out, int out_size, void* d_ws, size_t ws_size,
                              hipStream_t stream) {
  const float* hidden  = (const float*)d_in[0];
  const int*   mask    = (const int*)d_in[1];
  const int*   labels  = (const int*)d_in[2];
  const float* W       = (const float*)d_in[3];
  const float* bias    = (const float*)d_in[4];
  const float* start_t = (const float*)d_in[5];
  const float* end_t   = (const float*)d_in[6];
  const float* trans   = (const float*)d_in[7];
  float* out = (float*)d_out;

  float* logits  = (float*)d_ws;                      // 294912 floats
  float* segmat  = logits + (size_t)NROWS * NL;       // 64*8*81 floats
  float* num_den = segmat + (size_t)BB * NSEG * 81;   // 64 floats (num)
  int*   lens    = (int*)(num_den + 128);             // 64 ints
  int*   cnt     = lens + 64;                         // 64 ints (arrival)

  logits_kernel<<<2048, 256, 0, stream>>>(hidden, W, bias, mask, logits, lens,
                                          out, cnt);
  scan_kernel<<<128 + NLOGW, 64, 0, stream>>>(logits, labels, start_t, end_t,
                                              trans, out, num_den, lens,
                                              segmat, cnt);
}

// Round 7
// 247.751 us; speedup vs baseline: 1.2878x; 1.0130x over previous
//
#include <hip/hip_runtime.h>
#include <hip/hip_bf16.h>
#include <stdint.h>

constexpr int BB  = 64;    // batch
constexpr int SS  = 512;   // seq len
constexpr int HH  = 768;   // hidden
constexpr int NL  = 9;     // labels
constexpr int NROWS = BB * SS;          // 32768
constexpr int EMN   = SS * NL;          // 4608 emissions per batch
constexpr int NSEG  = 8;                // time segments for parallel lognorm
constexpr int NCH   = BB * NSEG * NL;   // 4608 lognorm basis chains
constexpr int GPW   = 7;                // chains (9-lane groups) per wave
constexpr int NLOGW = (NCH + GPW - 1) / GPW;  // 659 lognorm waves
constexpr float NEG  = -1e30f;

__device__ __forceinline__ float readlane_f(float v, int lane) {
  union { float f; int i; } u;
  u.f = v;
  u.i = __builtin_amdgcn_readlane(u.i, lane);
  return u.f;
}

// lane gather via LDS crossbar: out = v from lane (byte_addr/4).
// With a uniform byte_addr this is a broadcast of lane (byte_addr/4).
__device__ __forceinline__ float bperm_f(int byte_addr, float v) {
  union { float f; int i; } u;
  u.f = v;
  u.i = __builtin_amdgcn_ds_bpermute(byte_addr, u.i);
  return u.f;
}

// 3-input max, single instruction, depth-2 trees for 9-way max.
// EXACT: float max is associative/commutative for finite inputs (no rounding).
__device__ __forceinline__ float max3f(float a, float b, float c) {
  float d;
  asm("v_max3_f32 %0, %1, %2, %3" : "=v"(d) : "v"(a), "v"(b), "v"(c));
  return d;
}

__device__ __forceinline__ float max9f(const float* c) {
  return max3f(max3f(c[0], c[1], c[2]),
               max3f(c[3], c[4], c[5]),
               max3f(c[6], c[7], c[8]));
}

// ---------------------------------------------------------------------------
// Kernel 1: logits[b,s,l] = hidden[b,s,:] @ W[:,l] + bias[l]
// Register-blocked (W reloaded per j-slice). Blocks 0..63 compute lens[b];
// block 0 zeroes loss acc; block 1 zeroes the combine arrival counters.
// ---------------------------------------------------------------------------
__global__ __launch_bounds__(256, 4) void logits_kernel(
    const float* __restrict__ hidden, const float* __restrict__ W,
    const float* __restrict__ bias, const int* __restrict__ mask,
    float* __restrict__ logits, int* __restrict__ lens,
    float* __restrict__ out, int* __restrict__ cnt) {
  const int lane = threadIdx.x & 63;
  const int wid  = blockIdx.x * 4 + (threadIdx.x >> 6);   // 8192 waves

  if (blockIdx.x == 0 && threadIdx.x == 0) out[0] = 0.0f;
  if (blockIdx.x == 1 && threadIdx.x < BB) cnt[threadIdx.x] = 0;

  if (blockIdx.x < 64 && threadIdx.x < 64) {
    const int4* mp = (const int4*)(mask + blockIdx.x * SS);
    const int4 a = mp[threadIdx.x];
    const int4 c = mp[threadIdx.x + 64];
    int lsum = a.x + a.y + a.z + a.w + c.x + c.y + c.z + c.w;
#pragma unroll
    for (int off = 32; off >= 1; off >>= 1) lsum += __shfl_xor(lsum, off, 64);
    if (threadIdx.x == 0) lens[blockIdx.x] = lsum;
  }

  const float my_bias = (lane < NL) ? bias[lane] : 0.0f;

  const float4* hp[4];
#pragma unroll
  for (int r = 0; r < 4; ++r)
    hp[r] = (const float4*)(hidden + (size_t)(wid + r * 8192) * HH);

  float acc[4][NL];
#pragma unroll
  for (int r = 0; r < 4; ++r)
#pragma unroll
    for (int l = 0; l < NL; ++l) acc[r][l] = 0.0f;

#pragma unroll
  for (int j = 0; j < 3; ++j) {
    float w[4][NL];                      // only this j-slice of W lives
#pragma unroll
    for (int k = 0; k < 4; ++k) {
      const int r = lane * 4 + j * 256 + k;
#pragma unroll
      for (int l = 0; l < NL; ++l) w[k][l] = W[r * NL + l];
    }
#pragma unroll
    for (int r = 0; r < 4; ++r) {
      const float4 h = hp[r][lane + j * 64];
#pragma unroll
      for (int l = 0; l < NL; ++l)
        acc[r][l] += h.x * w[0][l] + h.y * w[1][l] +
                     h.z * w[2][l] + h.w * w[3][l];
    }
  }
#pragma unroll
  for (int off = 32; off >= 1; off >>= 1)
#pragma unroll
    for (int r = 0; r < 4; ++r)
#pragma unroll
      for (int l = 0; l < NL; ++l)
        acc[r][l] += __shfl_xor(acc[r][l], off, 64);
  if (lane < NL) {
#pragma unroll
    for (int r = 0; r < 4; ++r) {
      float v = acc[r][0];
#pragma unroll
      for (int l = 1; l < NL; ++l) if (lane == l) v = acc[r][l];
      logits[(size_t)(wid + r * 8192) * NL + lane] = v + my_bias;
    }
  }
}

// combine logic, run by the LAST arriving producer of each batch (73 total:
// 72 basis chains + 1 numerator). Bit-identical to the original combine.
__device__ void combine_batch(int b, int tid,
                              const float* __restrict__ logits,
                              const float* __restrict__ segmat,
                              const float* __restrict__ start_t,
                              const float* __restrict__ end_t,
                              const float* __restrict__ num_den,
                              float* __restrict__ out) {
  const int j = (tid < NL) ? tid : NL - 1;
  float s[NL];
#pragma unroll
  for (int i = 0; i < NL; ++i) s[i] = start_t[i] + logits[(size_t)b * EMN + i];
  float mcur[NL], mnxt[NL];
  {
    const float* M = segmat + (size_t)(b * NSEG) * 81;
#pragma unroll
    for (int i = 0; i < NL; ++i) mcur[i] = M[i * NL + j];
  }
  for (int sg = 0; sg < NSEG; ++sg) {
    if (sg + 1 < NSEG) {
      const float* M = segmat + (size_t)(b * NSEG + sg + 1) * 81;
#pragma unroll
      for (int i = 0; i < NL; ++i) mnxt[i] = M[i * NL + j];
    }
    float c[NL];
#pragma unroll
    for (int i = 0; i < NL; ++i) c[i] = s[i] + mcur[i];
    const float m = max9f(c);
    float sum = 0.0f;
#pragma unroll
    for (int i = 0; i < NL; ++i) sum += __expf(c[i] - m);
    const float nxt = m + __logf(sum);
#pragma unroll
    for (int i = 0; i < NL; ++i) s[i] = readlane_f(nxt, i);
#pragma unroll
    for (int i = 0; i < NL; ++i) mcur[i] = mnxt[i];
  }
  float c[NL];
#pragma unroll
  for (int i = 0; i < NL; ++i) c[i] = s[i] + end_t[i];
  const float m = max9f(c);
  float sum = 0.0f;
#pragma unroll
  for (int i = 0; i < NL; ++i) sum += __expf(c[i] - m);
  if (tid == 0) {
    const float den = m + __logf(sum);
    atomicAdd(out, (den - num_den[b]) * (1.0f / 64.0f));
  }
}

// ---------------------------------------------------------------------------
// Kernel 2: scan kernel, 787 one-wave blocks.
//   blk   0..  63 : viterbi — state broadcast via 9 pipelined ds_bpermute
//                   (replaces 9 serializing v_readlane, the suspected ~250
//                   cyc/step hazard cost). Arithmetic identical -> bit-exact.
//   blk  64.. 127 : numerator
//   blk 128.. 786 : lognorm, 7 chains per wave in 9-lane groups
//   Last arriving producer per batch runs combine in-place.
// ---------------------------------------------------------------------------
__global__ __launch_bounds__(64) void scan_kernel(
    const float* __restrict__ logits, const int* __restrict__ labels,
    const float* __restrict__ start_t, const float* __restrict__ end_t,
    const float* __restrict__ trans, float* __restrict__ out,
    float* __restrict__ num_den, const int* __restrict__ lens,
    float* __restrict__ segmat, int* __restrict__ cnt) {
  __shared__ uint32_t bpw[64 * NL];             // packed backpointers: 2304 B
  __shared__ unsigned char tags_s[SS];
  __shared__ unsigned char lab[SS];

  const int blk = blockIdx.x;
  const int tid = threadIdx.x;
  const int j   = (tid < NL) ? tid : NL - 1;

  if (blk < 64) {
    // ================= viterbi =================
    __builtin_amdgcn_s_setprio(1);
    const int b   = blk;
    const int len = lens[b];            // len >= 256 by construction
    const float* emb = logits + (size_t)b * EMN;

    float tc[NL];
#pragma unroll
    for (int i = 0; i < NL; ++i) tc[i] = trans[i * NL + j];
    // state replicated across lanes in VGPRs (all lanes hold all 9 values)
    float s[NL];
#pragma unroll
    for (int i = 0; i < NL; ++i) s[i] = start_t[i] + emb[i];

    // emission double-buffer: block tb covers t = 8*tb+1 .. 8*tb+8
    float e0[8], e1[8];
#pragma unroll
    for (int k = 0; k < 8; ++k) e0[k] = emb[(1 + k) * NL + j];

    const int nfull = (len - 1) >> 3;   // full 8-step blocks (no guards inside)
    for (int tb = 0; tb < nfull; ++tb) {
      const int tbase = 8 * tb;
      // prefetch next block's emissions (max row 512 for len=512: reads 9
      // floats past this batch's logits -> next batch / segmat, harmless,
      // never consumed since t=512 >= len always).
#pragma unroll
      for (int k = 0; k < 8; ++k) e1[k] = emb[(tbase + 9 + k) * NL + j];
      uint32_t wpk = 0;
#pragma unroll
      for (int k = 0; k < 8; ++k) {
        float c[NL];
#pragma unroll
        for (int i = 0; i < NL; ++i) c[i] = s[i] + tc[i];
        const float best = max9f(c);          // critical path: depth-2 max3
        const float nxt  = best + e0[k];
        {                                     // off-path argmax (ref ties)
          const bool b01 = c[0] >= c[1], b23 = c[2] >= c[3];
          const bool b45 = c[4] >= c[5], b67 = c[6] >= c[7];
          const float v01 = b01 ? c[0] : c[1]; const int i01 = b01 ? 0 : 1;
          const float v23 = b23 ? c[2] : c[3]; const int i23 = b23 ? 2 : 3;
          const float v45 = b45 ? c[4] : c[5]; const int i45 = b45 ? 4 : 5;
          const float v67 = b67 ? c[6] : c[7]; const int i67 = b67 ? 6 : 7;
          const bool bA = v01 >= v23, bB = v45 >= v67;
          const float vA = bA ? v01 : v23; const int iA = bA ? i01 : i23;
          const float vB = bB ? v45 : v67; const int iB = bB ? i45 : i67;
          const bool bC = vA >= vB;
          const float vC = bC ? vA : vB; const int iC = bC ? iA : iB;
          const bool bD = vC >= c[8];
          const int arg = bD ? iC : 8;
          wpk |= (uint32_t)arg << (4 * k);
        }
        // broadcast new state: lane i's nxt -> s[i] in every lane.
        // 9 bpermutes pipeline on the LDS crossbar; the argmax tree above
        // has no dependence on them and issues under their latency.
#pragma unroll
        for (int i = 0; i < NL; ++i) s[i] = bperm_f(4 * i, nxt);
      }
      if (tid < NL) bpw[tb * NL + tid] = wpk;
#pragma unroll
      for (int k = 0; k < 8; ++k) e0[k] = e1[k];
    }
    // tail: t = 8*nfull+1 .. len-1 (0..7 steps), emissions already in e0
    {
      const int tbase = 8 * nfull;
      uint32_t wpk = 0;
#pragma unroll
      for (int k = 0; k < 8; ++k) {
        const int t = tbase + 1 + k;
        if (t < len) {                         // wave-uniform guard
          float c[NL];
#pragma unroll
          for (int i = 0; i < NL; ++i) c[i] = s[i] + tc[i];
          const float best = max9f(c);
          const float nxt  = best + e0[k];
          {
            const bool b01 = c[0] >= c[1], b23 = c[2] >= c[3];
            const bool b45 = c[4] >= c[5], b67 = c[6] >= c[7];
            const float v01 = b01 ? c[0] : c[1]; const int i01 = b01 ? 0 : 1;
            const float v23 = b23 ? c[2] : c[3]; const int i23 = b23 ? 2 : 3;
            const float v45 = b45 ? c[4] : c[5]; const int i45 = b45 ? 4 : 5;
            const float v67 = b67 ? c[6] : c[7]; const int i67 = b67 ? 6 : 7;
            const bool bA = v01 >= v23, bB = v45 >= v67;
            const float vA = bA ? v01 : v23; const int iA = bA ? i01 : i23;
            const float vB = bB ? v45 : v67; const int iB = bB ? i45 : i67;
            const bool bC = vA >= vB;
            const float vC = bC ? vA : vB; const int iC = bC ? iA : iB;
            const bool bD = vC >= c[8];
            const int arg = bD ? iC : 8;
            wpk |= (uint32_t)arg << (4 * k);
          }
#pragma unroll
          for (int i = 0; i < NL; ++i) s[i] = bperm_f(4 * i, nxt);
        }
      }
      if (nfull < 64 && tid < NL) bpw[nfull * NL + tid] = wpk;
    }
    float bv = s[0] + end_t[0];
    int   bl = 0;
#pragma unroll
    for (int i = 1; i < NL; ++i) {
      const float cc = s[i] + end_t[i];
      if (cc > bv) { bv = cc; bl = i; }
    }
    __syncthreads();

    // backtrace: chunked map composition over packed backpointer words
    uint32_t wv_[NL];
#pragma unroll
    for (int x = 0; x < NL; ++x) wv_[x] = bpw[tid * NL + x];
    uint64_t C = 0x876543210ULL;
#pragma unroll
    for (int k = 1; k <= 8; ++k) {
      const int t = 8 * tid + k;
      uint64_t nc = 0;
#pragma unroll
      for (int x = 0; x < 9; ++x) {
        const int g = (int)((wv_[x] >> (4 * (k - 1))) & 15u);
        nc |= ((C >> (4 * g)) & 15ULL) << (4 * x);
      }
      C = (t < len) ? nc : C;
    }
    const uint32_t Clo = (uint32_t)C, Chi = (uint32_t)(C >> 32);
    uint32_t cur = (uint32_t)bl;
    int bnd = 0;
#pragma unroll
    for (int c = 63; c >= 0; --c) {
      bnd = (tid == c) ? (int)cur : bnd;
      const uint32_t lo = (uint32_t)__builtin_amdgcn_readlane((int)Clo, c);
      const uint32_t hi = (uint32_t)__builtin_amdgcn_readlane((int)Chi, c);
      const uint64_t cc = ((uint64_t)hi << 32) | lo;
      cur = (uint32_t)((cc >> (4 * cur)) & 15u);
    }
    int tag = bnd;
#pragma unroll
    for (int k = 8; k >= 1; --k) {
      const int t = 8 * tid + k;
      const int tt = (t < 512) ? t : 511;
      const int blk2 = (tt - 1) >> 3;
      const int kk   = tt - 8 * blk2;
      const uint32_t bw = bpw[blk2 * NL + tag];
      const int nt = (int)((bw >> (4 * (kk - 1))) & 15u);
      tag = (t < len) ? nt : tag;
      tags_s[t - 1] = (unsigned char)tag;
    }
    __syncthreads();
    for (int i = tid; i < EMN; i += 64) {
      const int t = i / NL;
      const int l = i - t * NL;
      out[1 + (size_t)b * EMN + i] =
          (t < len && l == (int)tags_s[t]) ? 1.0f : 0.0f;
    }

  } else if (blk < 128) {
    // ================= numerator =================
    const int b   = blk - 64;
    const int len = lens[b];
    const float* emb = logits + (size_t)b * EMN;
    for (int t = tid; t < SS; t += 64) {
      const int v = labels[b * SS + t];
      lab[t] = (unsigned char)((v == -100) ? 0 : v);
    }
    __syncthreads();
    float contrib = 0.0f;
    for (int t = tid; t < SS; t += 64) {
      if (t >= 1 && t < len)
        contrib += emb[t * NL + lab[t]] + trans[lab[t - 1] * NL + lab[t]];
    }
#pragma unroll
    for (int off = 32; off >= 1; off >>= 1)
      contrib += __shfl_xor(contrib, off, 64);
    if (tid == 0) {
      const int l0 = lab[0];
      num_den[b] = start_t[l0] + emb[l0] + contrib + end_t[lab[len - 1]];
    }
    __threadfence();
    int old = -1;
    if (tid == 0) old = atomicAdd(&cnt[b], 1);
    old = __builtin_amdgcn_readlane(old, 0);
    if (old == 72) {
      __threadfence();
      combine_batch(b, tid, logits, segmat, start_t, end_t, num_den, out);
    }

  } else {
    // ============ lognorm: 7 chains per wave, 9-lane groups ============
    const int w   = blk - 128;               // 0..658
    const int g   = tid / 9;                 // 0..7 (g==7: lane 63, idle)
    const int i   = tid - 9 * g;             // state index within group
    const int cid = GPW * w + g;
    const bool valid = (g < GPW) && (cid < NCH);
    const int cc  = valid ? cid : (NCH - 1); // idle lanes duplicate last chain
    const int pr  = cc / 9;                  // (b, sg) pair
    const int e   = cc - 9 * pr;             // basis index
    const int b   = pr >> 3;
    const int sg  = pr & 7;
    const int len = lens[b];
    const int base4 = (g < GPW) ? (9 * g * 4) : 0;   // group gather base
    const float* embp = logits + (size_t)b * EMN + i;

    float tc[NL];
#pragma unroll
    for (int k = 0; k < NL; ++k) tc[k] = trans[k * NL + i];
    float my = (i == e) ? 0.0f : NEG;        // basis initial state
    const int tbeg = 64 * sg + 1;

    // rolling 4-deep emission prefetch (per-lane column i of row t).
    // max read index (64*sg+68)*9+8 for sg=7, b=63 lands in segmat: harmless.
    float eA = embp[(size_t)(tbeg    ) * NL], eB = embp[(size_t)(tbeg + 1) * NL];
    float eC = embp[(size_t)(tbeg + 2) * NL], eD = embp[(size_t)(tbeg + 3) * NL];

    for (int st = 0; st < 64; ++st) {
      const int t = tbeg + st;               // per-lane absolute time
      if (__ballot((g < GPW) && (t < len)) == 0ull) break;
      float s[NL], c[NL];
#pragma unroll
      for (int k = 0; k < NL; ++k) s[k] = bperm_f(base4 + 4 * k, my);
#pragma unroll
      for (int k = 0; k < NL; ++k) c[k] = s[k] + tc[k];
      const float m = max9f(c);
      float u = 0.0f;
#pragma unroll
      for (int k = 0; k < NL; ++k) u += __expf(c[k] - m);
      const float nv = m + __logf(u) + eA;
      my = (t < len) ? nv : my;              // reference mask semantics
      eA = eB; eB = eC; eC = eD;
      eD = embp[(size_t)(t + 4) * NL];
    }
    if (valid) segmat[(size_t)pr * 81 + e * NL + i] = my;
    __threadfence();
    int old = -1;
    if (valid && i == 0) old = atomicAdd(&cnt[b], 1);
#pragma unroll
    for (int g2 = 0; g2 < GPW; ++g2) {
      const int og = __builtin_amdgcn_readlane(old, 9 * g2);
      if (og == 72) {
        const int bg = __builtin_amdgcn_readlane(b, 9 * g2);
        __threadfence();
        combine_batch(bg, tid, logits, segmat, start_t, end_t, num_den, out);
      }
    }
  }
}

extern "C" void kernel_launch(void* const* d_in, const int* in_sizes, int n_in,
                              void* d_out, int out_size, void* d_ws, size_t ws_size,
                              hipStream_t stream) {
  const float* hidden  = (const float*)d_in[0];
  const int*   mask    = (const int*)d_in[1];
  const int*   labels  = (const int*)d_in[2];
  const float* W       = (const float*)d_in[3];
  const float* bias    = (const float*)d_in[4];
  const float* start_t = (const float*)d_in[5];
  const float* end_t   = (const float*)d_in[6];
  const float* trans   = (const float*)d_in[7];
  float* out = (float*)d_out;

  float* logits  = (float*)d_ws;                      // 294912 floats
  float* segmat  = logits + (size_t)NROWS * NL;       // 64*8*81 floats
  float* num_den = segmat + (size_t)BB * NSEG * 81;   // 64 floats (num)
  int*   lens    = (int*)(num_den + 128);             // 64 ints
  int*   cnt     = lens + 64;                         // 64 ints (arrival)

  logits_kernel<<<2048, 256, 0, stream>>>(hidden, W, bias, mask, logits, lens,
                                          out, cnt);
  scan_kernel<<<128 + NLOGW, 64, 0, stream>>>(logits, labels, start_t, end_t,
                                              trans, out, num_den, lens,
                                              segmat, cnt);
}

// Round 8
// 241.964 us; speedup vs baseline: 1.3186x; 1.0239x over previous
//
#include <hip/hip_runtime.h>
#include <hip/hip_bf16.h>
#include <stdint.h>

constexpr int BB  = 64;    // batch
constexpr int SS  = 512;   // seq len
constexpr int HH  = 768;   // hidden
constexpr int NL  = 9;     // labels
constexpr int NROWS = BB * SS;          // 32768
constexpr int EMN   = SS * NL;          // 4608 emissions per batch
constexpr int NSEG  = 8;                // time segments for parallel lognorm
constexpr int NCH   = BB * NSEG * NL;   // 4608 lognorm basis chains
constexpr int GPW   = 7;                // chains (9-lane groups) per wave
constexpr int NLOGW = (NCH + GPW - 1) / GPW;  // 659 lognorm waves
constexpr float NEG  = -1e30f;

__device__ __forceinline__ float readlane_f(float v, int lane) {
  union { float f; int i; } u;
  u.f = v;
  u.i = __builtin_amdgcn_readlane(u.i, lane);
  return u.f;
}

// lane gather via LDS crossbar (per-lane VGPR address)
__device__ __forceinline__ float bperm_f(int byte_addr, float v) {
  union { float f; int i; } u;
  u.f = v;
  u.i = __builtin_amdgcn_ds_bpermute(byte_addr, u.i);
  return u.f;
}

// broadcast lane I (0..31, within each 32-lane half) to all lanes via
// ds_swizzle BitMode: offset = (xor<<10)|(or<<5)|and, and=0, or=I, xor=0.
// Compile-time immediate, no address VGPR.
#define SWZ_BCAST(dst, src, I)                                        \
  { union { float f; int i; } _u; _u.f = (src);                       \
    _u.i = __builtin_amdgcn_ds_swizzle(_u.i, ((I) << 5));             \
    (dst) = _u.f; }

// 3-input max, single instruction, depth-2 trees for 9-way max.
// EXACT: float max is associative/commutative for finite inputs (no rounding).
__device__ __forceinline__ float max3f(float a, float b, float c) {
  float d;
  asm("v_max3_f32 %0, %1, %2, %3" : "=v"(d) : "v"(a), "v"(b), "v"(c));
  return d;
}

__device__ __forceinline__ float max9f(const float* c) {
  return max3f(max3f(c[0], c[1], c[2]),
               max3f(c[3], c[4], c[5]),
               max3f(c[6], c[7], c[8]));
}

// ---------------------------------------------------------------------------
// Kernel 1: logits[b,s,l] = hidden[b,s,:] @ W[:,l] + bias[l]
// Register-blocked (W reloaded per j-slice). Blocks 0..63 compute lens[b];
// block 0 zeroes loss acc; block 1 zeroes the combine arrival counters.
// ---------------------------------------------------------------------------
__global__ __launch_bounds__(256, 4) void logits_kernel(
    const float* __restrict__ hidden, const float* __restrict__ W,
    const float* __restrict__ bias, const int* __restrict__ mask,
    float* __restrict__ logits, int* __restrict__ lens,
    float* __restrict__ out, int* __restrict__ cnt) {
  const int lane = threadIdx.x & 63;
  const int wid  = blockIdx.x * 4 + (threadIdx.x >> 6);   // 8192 waves

  if (blockIdx.x == 0 && threadIdx.x == 0) out[0] = 0.0f;
  if (blockIdx.x == 1 && threadIdx.x < BB) cnt[threadIdx.x] = 0;

  if (blockIdx.x < 64 && threadIdx.x < 64) {
    const int4* mp = (const int4*)(mask + blockIdx.x * SS);
    const int4 a = mp[threadIdx.x];
    const int4 c = mp[threadIdx.x + 64];
    int lsum = a.x + a.y + a.z + a.w + c.x + c.y + c.z + c.w;
#pragma unroll
    for (int off = 32; off >= 1; off >>= 1) lsum += __shfl_xor(lsum, off, 64);
    if (threadIdx.x == 0) lens[blockIdx.x] = lsum;
  }

  const float my_bias = (lane < NL) ? bias[lane] : 0.0f;

  const float4* hp[4];
#pragma unroll
  for (int r = 0; r < 4; ++r)
    hp[r] = (const float4*)(hidden + (size_t)(wid + r * 8192) * HH);

  float acc[4][NL];
#pragma unroll
  for (int r = 0; r < 4; ++r)
#pragma unroll
    for (int l = 0; l < NL; ++l) acc[r][l] = 0.0f;

#pragma unroll
  for (int j = 0; j < 3; ++j) {
    float w[4][NL];                      // only this j-slice of W lives
#pragma unroll
    for (int k = 0; k < 4; ++k) {
      const int r = lane * 4 + j * 256 + k;
#pragma unroll
      for (int l = 0; l < NL; ++l) w[k][l] = W[r * NL + l];
    }
#pragma unroll
    for (int r = 0; r < 4; ++r) {
      const float4 h = hp[r][lane + j * 64];
#pragma unroll
      for (int l = 0; l < NL; ++l)
        acc[r][l] += h.x * w[0][l] + h.y * w[1][l] +
                     h.z * w[2][l] + h.w * w[3][l];
    }
  }
#pragma unroll
  for (int off = 32; off >= 1; off >>= 1)
#pragma unroll
    for (int r = 0; r < 4; ++r)
#pragma unroll
      for (int l = 0; l < NL; ++l)
        acc[r][l] += __shfl_xor(acc[r][l], off, 64);
  if (lane < NL) {
#pragma unroll
    for (int r = 0; r < 4; ++r) {
      float v = acc[r][0];
#pragma unroll
      for (int l = 1; l < NL; ++l) if (lane == l) v = acc[r][l];
      logits[(size_t)(wid + r * 8192) * NL + lane] = v + my_bias;
    }
  }
}

// combine logic, run by the LAST arriving producer of each batch (73 total:
// 72 basis chains + 1 numerator). Bit-identical to the original combine.
__device__ void combine_batch(int b, int tid,
                              const float* __restrict__ logits,
                              const float* __restrict__ segmat,
                              const float* __restrict__ start_t,
                              const float* __restrict__ end_t,
                              const float* __restrict__ num_den,
                              float* __restrict__ out) {
  const int j = (tid < NL) ? tid : NL - 1;
  float s[NL];
#pragma unroll
  for (int i = 0; i < NL; ++i) s[i] = start_t[i] + logits[(size_t)b * EMN + i];
  float mcur[NL], mnxt[NL];
  {
    const float* M = segmat + (size_t)(b * NSEG) * 81;
#pragma unroll
    for (int i = 0; i < NL; ++i) mcur[i] = M[i * NL + j];
  }
  for (int sg = 0; sg < NSEG; ++sg) {
    if (sg + 1 < NSEG) {
      const float* M = segmat + (size_t)(b * NSEG + sg + 1) * 81;
#pragma unroll
      for (int i = 0; i < NL; ++i) mnxt[i] = M[i * NL + j];
    }
    float c[NL];
#pragma unroll
    for (int i = 0; i < NL; ++i) c[i] = s[i] + mcur[i];
    const float m = max9f(c);
    float sum = 0.0f;
#pragma unroll
    for (int i = 0; i < NL; ++i) sum += __expf(c[i] - m);
    const float nxt = m + __logf(sum);
#pragma unroll
    for (int i = 0; i < NL; ++i) s[i] = readlane_f(nxt, i);
#pragma unroll
    for (int i = 0; i < NL; ++i) mcur[i] = mnxt[i];
  }
  float c[NL];
#pragma unroll
  for (int i = 0; i < NL; ++i) c[i] = s[i] + end_t[i];
  const float m = max9f(c);
  float sum = 0.0f;
#pragma unroll
  for (int i = 0; i < NL; ++i) sum += __expf(c[i] - m);
  if (tid == 0) {
    const float den = m + __logf(sum);
    atomicAdd(out, (den - num_den[b]) * (1.0f / 64.0f));
  }
}

// ---------------------------------------------------------------------------
// Kernel 2: scan kernel, 787 one-wave blocks.
//   blk   0..  63 : viterbi — DS-PURE serial loop: emissions staged to LDS
//                   pre-loop, e-prefetch via ds_read, broadcast via 9
//                   compile-time ds_swizzle. NO global/flat ops in the loop,
//                   so the per-step lgkmcnt wait covers only short LDS-class
//                   latency (theory: flat loads were poisoning lgkmcnt with
//                   L3-class latency every step).
//   blk  64.. 127 : numerator
//   blk 128.. 786 : lognorm, 7 chains per wave in 9-lane groups
//   Last arriving producer per batch runs combine in-place.
// ---------------------------------------------------------------------------
__global__ __launch_bounds__(64) void scan_kernel(
    const float* __restrict__ logits, const int* __restrict__ labels,
    const float* __restrict__ start_t, const float* __restrict__ end_t,
    const float* __restrict__ trans, float* __restrict__ out,
    float* __restrict__ num_den, const int* __restrict__ lens,
    float* __restrict__ segmat, int* __restrict__ cnt) {
  __shared__ float4   embv[1161];               // staged emissions, 18576 B
  __shared__ uint32_t bpw[64 * NL];             // packed backpointers: 2304 B
  __shared__ unsigned char tags_s[SS];
  __shared__ unsigned char lab[SS];

  const int blk = blockIdx.x;
  const int tid = threadIdx.x;
  const int j   = (tid < NL) ? tid : NL - 1;

  if (blk < 64) {
    // ================= viterbi =================
    __builtin_amdgcn_s_setprio(1);
    const int b   = blk;
    const int len = lens[b];            // len >= 256 by construction
    const float* emb = logits + (size_t)b * EMN;

    // stage this batch's emissions into LDS (one coalesced burst; the only
    // global reads the viterbi path performs)
    {
      const float4* src = (const float4*)emb;
#pragma unroll
      for (int i = 0; i < 18; ++i) embv[tid + i * 64] = src[tid + i * 64];
    }
    __syncthreads();
    const float* emb_s = (const float*)embv;

    float tc[NL];
#pragma unroll
    for (int i = 0; i < NL; ++i) tc[i] = trans[i * NL + j];
    // state replicated across lanes (lanes 0..31 always correct; upper half
    // may hold garbage after swizzle-broadcast — nothing consumes it)
    float s[NL];
#pragma unroll
    for (int i = 0; i < NL; ++i) s[i] = start_t[i] + emb_s[i];

    // emission double-buffer (LDS reads): block tb covers t = 8*tb+1..8*tb+8
    float e0[8], e1[8];
#pragma unroll
    for (int k = 0; k < 8; ++k) e0[k] = emb_s[(1 + k) * NL + j];

    const int nfull = (len - 1) >> 3;   // full 8-step blocks (no guards inside)
    for (int tb = 0; tb < nfull; ++tb) {
      const int tbase = 8 * tb;
      // prefetch next block's emissions from LDS (short-latency ds_read;
      // max index 4616 < 4644: staged-pad covers it, values never consumed)
#pragma unroll
      for (int k = 0; k < 8; ++k) e1[k] = emb_s[(tbase + 9 + k) * NL + j];
      uint32_t wpk = 0;
#pragma unroll
      for (int k = 0; k < 8; ++k) {
        float c[NL];
#pragma unroll
        for (int i = 0; i < NL; ++i) c[i] = s[i] + tc[i];
        const float best = max9f(c);          // critical path: depth-2 max3
        const float nxt  = best + e0[k];
        // broadcast new state: lane i's nxt -> s[i] (lanes 0..31 correct)
        SWZ_BCAST(s[0], nxt, 0); SWZ_BCAST(s[1], nxt, 1);
        SWZ_BCAST(s[2], nxt, 2); SWZ_BCAST(s[3], nxt, 3);
        SWZ_BCAST(s[4], nxt, 4); SWZ_BCAST(s[5], nxt, 5);
        SWZ_BCAST(s[6], nxt, 6); SWZ_BCAST(s[7], nxt, 7);
        SWZ_BCAST(s[8], nxt, 8);
        {                                     // off-path argmax (ref ties)
          const bool b01 = c[0] >= c[1], b23 = c[2] >= c[3];
          const bool b45 = c[4] >= c[5], b67 = c[6] >= c[7];
          const float v01 = b01 ? c[0] : c[1]; const int i01 = b01 ? 0 : 1;
          const float v23 = b23 ? c[2] : c[3]; const int i23 = b23 ? 2 : 3;
          const float v45 = b45 ? c[4] : c[5]; const int i45 = b45 ? 4 : 5;
          const float v67 = b67 ? c[6] : c[7]; const int i67 = b67 ? 6 : 7;
          const bool bA = v01 >= v23, bB = v45 >= v67;
          const float vA = bA ? v01 : v23; const int iA = bA ? i01 : i23;
          const float vB = bB ? v45 : v67; const int iB = bB ? i45 : i67;
          const bool bC = vA >= vB;
          const float vC = bC ? vA : vB; const int iC = bC ? iA : iB;
          const bool bD = vC >= c[8];
          const int arg = bD ? iC : 8;
          wpk |= (uint32_t)arg << (4 * k);
        }
      }
      if (tid < NL) bpw[tb * NL + tid] = wpk;
#pragma unroll
      for (int k = 0; k < 8; ++k) e0[k] = e1[k];
    }
    // tail: t = 8*nfull+1 .. len-1 (0..7 steps), emissions already in e0
    {
      const int tbase = 8 * nfull;
      uint32_t wpk = 0;
#pragma unroll
      for (int k = 0; k < 8; ++k) {
        const int t = tbase + 1 + k;
        if (t < len) {                         // wave-uniform guard
          float c[NL];
#pragma unroll
          for (int i = 0; i < NL; ++i) c[i] = s[i] + tc[i];
          const float best = max9f(c);
          const float nxt  = best + e0[k];
          SWZ_BCAST(s[0], nxt, 0); SWZ_BCAST(s[1], nxt, 1);
          SWZ_BCAST(s[2], nxt, 2); SWZ_BCAST(s[3], nxt, 3);
          SWZ_BCAST(s[4], nxt, 4); SWZ_BCAST(s[5], nxt, 5);
          SWZ_BCAST(s[6], nxt, 6); SWZ_BCAST(s[7], nxt, 7);
          SWZ_BCAST(s[8], nxt, 8);
          {
            const bool b01 = c[0] >= c[1], b23 = c[2] >= c[3];
            const bool b45 = c[4] >= c[5], b67 = c[6] >= c[7];
            const float v01 = b01 ? c[0] : c[1]; const int i01 = b01 ? 0 : 1;
            const float v23 = b23 ? c[2] : c[3]; const int i23 = b23 ? 2 : 3;
            const float v45 = b45 ? c[4] : c[5]; const int i45 = b45 ? 4 : 5;
            const float v67 = b67 ? c[6] : c[7]; const int i67 = b67 ? 6 : 7;
            const bool bA = v01 >= v23, bB = v45 >= v67;
            const float vA = bA ? v01 : v23; const int iA = bA ? i01 : i23;
            const float vB = bB ? v45 : v67; const int iB = bB ? i45 : i67;
            const bool bC = vA >= vB;
            const float vC = bC ? vA : vB; const int iC = bC ? iA : iB;
            const bool bD = vC >= c[8];
            const int arg = bD ? iC : 8;
            wpk |= (uint32_t)arg << (4 * k);
          }
        }
      }
      if (nfull < 64 && tid < NL) bpw[nfull * NL + tid] = wpk;
    }
    // fix-up: upper-half lanes hold garbage state; rebroadcast from lane 0
    // (lane 0 is in the always-correct lower half) so every lane's backtrace
    // inputs are exact.
#pragma unroll
    for (int i = 0; i < NL; ++i) s[i] = readlane_f(s[i], 0);
    float bv = s[0] + end_t[0];
    int   bl = 0;
#pragma unroll
    for (int i = 1; i < NL; ++i) {
      const float cc = s[i] + end_t[i];
      if (cc > bv) { bv = cc; bl = i; }
    }
    __syncthreads();

    // backtrace: chunked map composition over packed backpointer words
    uint32_t wv_[NL];
#pragma unroll
    for (int x = 0; x < NL; ++x) wv_[x] = bpw[tid * NL + x];
    uint64_t C = 0x876543210ULL;
#pragma unroll
    for (int k = 1; k <= 8; ++k) {
      const int t = 8 * tid + k;
      uint64_t nc = 0;
#pragma unroll
      for (int x = 0; x < 9; ++x) {
        const int g = (int)((wv_[x] >> (4 * (k - 1))) & 15u);
        nc |= ((C >> (4 * g)) & 15ULL) << (4 * x);
      }
      C = (t < len) ? nc : C;
    }
    const uint32_t Clo = (uint32_t)C, Chi = (uint32_t)(C >> 32);
    uint32_t cur = (uint32_t)bl;
    int bnd = 0;
#pragma unroll
    for (int c = 63; c >= 0; --c) {
      bnd = (tid == c) ? (int)cur : bnd;
      const uint32_t lo = (uint32_t)__builtin_amdgcn_readlane((int)Clo, c);
      const uint32_t hi = (uint32_t)__builtin_amdgcn_readlane((int)Chi, c);
      const uint64_t cc = ((uint64_t)hi << 32) | lo;
      cur = (uint32_t)((cc >> (4 * cur)) & 15u);
    }
    int tag = bnd;
#pragma unroll
    for (int k = 8; k >= 1; --k) {
      const int t = 8 * tid + k;
      const int tt = (t < 512) ? t : 511;
      const int blk2 = (tt - 1) >> 3;
      const int kk   = tt - 8 * blk2;
      const uint32_t bw = bpw[blk2 * NL + tag];
      const int nt = (int)((bw >> (4 * (kk - 1))) & 15u);
      tag = (t < len) ? nt : tag;
      tags_s[t - 1] = (unsigned char)tag;
    }
    __syncthreads();
    for (int i = tid; i < EMN; i += 64) {
      const int t = i / NL;
      const int l = i - t * NL;
      out[1 + (size_t)b * EMN + i] =
          (t < len && l == (int)tags_s[t]) ? 1.0f : 0.0f;
    }

  } else if (blk < 128) {
    // ================= numerator =================
    const int b   = blk - 64;
    const int len = lens[b];
    const float* emb = logits + (size_t)b * EMN;
    for (int t = tid; t < SS; t += 64) {
      const int v = labels[b * SS + t];
      lab[t] = (unsigned char)((v == -100) ? 0 : v);
    }
    __syncthreads();
    float contrib = 0.0f;
    for (int t = tid; t < SS; t += 64) {
      if (t >= 1 && t < len)
        contrib += emb[t * NL + lab[t]] + trans[lab[t - 1] * NL + lab[t]];
    }
#pragma unroll
    for (int off = 32; off >= 1; off >>= 1)
      contrib += __shfl_xor(contrib, off, 64);
    if (tid == 0) {
      const int l0 = lab[0];
      num_den[b] = start_t[l0] + emb[l0] + contrib + end_t[lab[len - 1]];
    }
    __threadfence();
    int old = -1;
    if (tid == 0) old = atomicAdd(&cnt[b], 1);
    old = __builtin_amdgcn_readlane(old, 0);
    if (old == 72) {
      __threadfence();
      combine_batch(b, tid, logits, segmat, start_t, end_t, num_den, out);
    }

  } else {
    // ============ lognorm: 7 chains per wave, 9-lane groups ============
    const int w   = blk - 128;               // 0..658
    const int g   = tid / 9;                 // 0..7 (g==7: lane 63, idle)
    const int i   = tid - 9 * g;             // state index within group
    const int cid = GPW * w + g;
    const bool valid = (g < GPW) && (cid < NCH);
    const int cc  = valid ? cid : (NCH - 1); // idle lanes duplicate last chain
    const int pr  = cc / 9;                  // (b, sg) pair
    const int e   = cc - 9 * pr;             // basis index
    const int b   = pr >> 3;
    const int sg  = pr & 7;
    const int len = lens[b];
    const int base4 = (g < GPW) ? (9 * g * 4) : 0;   // group gather base
    const float* embp = logits + (size_t)b * EMN + i;

    float tc[NL];
#pragma unroll
    for (int k = 0; k < NL; ++k) tc[k] = trans[k * NL + i];
    float my = (i == e) ? 0.0f : NEG;        // basis initial state
    const int tbeg = 64 * sg + 1;

    // rolling 4-deep emission prefetch (per-lane column i of row t).
    // max read index (64*sg+68)*9+8 for sg=7, b=63 lands in segmat: harmless.
    float eA = embp[(size_t)(tbeg    ) * NL], eB = embp[(size_t)(tbeg + 1) * NL];
    float eC = embp[(size_t)(tbeg + 2) * NL], eD = embp[(size_t)(tbeg + 3) * NL];

    for (int st = 0; st < 64; ++st) {
      const int t = tbeg + st;               // per-lane absolute time
      if (__ballot((g < GPW) && (t < len)) == 0ull) break;
      float s[NL], c[NL];
#pragma unroll
      for (int k = 0; k < NL; ++k) s[k] = bperm_f(base4 + 4 * k, my);
#pragma unroll
      for (int k = 0; k < NL; ++k) c[k] = s[k] + tc[k];
      const float m = max9f(c);
      float u = 0.0f;
#pragma unroll
      for (int k = 0; k < NL; ++k) u += __expf(c[k] - m);
      const float nv = m + __logf(u) + eA;
      my = (t < len) ? nv : my;              // reference mask semantics
      eA = eB; eB = eC; eC = eD;
      eD = embp[(size_t)(t + 4) * NL];
    }
    if (valid) segmat[(size_t)pr * 81 + e * NL + i] = my;
    __threadfence();
    int old = -1;
    if (valid && i == 0) old = atomicAdd(&cnt[b], 1);
#pragma unroll
    for (int g2 = 0; g2 < GPW; ++g2) {
      const int og = __builtin_amdgcn_readlane(old, 9 * g2);
      if (og == 72) {
        const int bg = __builtin_amdgcn_readlane(b, 9 * g2);
        __threadfence();
        combine_batch(bg, tid, logits, segmat, start_t, end_t, num_den, out);
      }
    }
  }
}

extern "C" void kernel_launch(void* const* d_in, const int* in_sizes, int n_in,
                              void* d_out, int out_size, void* d_ws, size_t ws_size,
                              hipStream_t stream) {
  const float* hidden  = (const float*)d_in[0];
  const int*   mask    = (const int*)d_in[1];
  const int*   labels  = (const int*)d_in[2];
  const float* W       = (const float*)d_in[3];
  const float* bias    = (const float*)d_in[4];
  const float* start_t = (const float*)d_in[5];
  const float* end_t   = (const float*)d_in[6];
  const float* trans   = (const float*)d_in[7];
  float* out = (float*)d_out;

  float* logits  = (float*)d_ws;                      // 294912 floats
  float* segmat  = logits + (size_t)NROWS * NL;       // 64*8*81 floats
  float* num_den = segmat + (size_t)BB * NSEG * 81;   // 64 floats (num)
  int*   lens    = (int*)(num_den + 128);             // 64 ints
  int*   cnt     = lens + 64;                         // 64 ints (arrival)

  logits_kernel<<<2048, 256, 0, stream>>>(hidden, W, bias, mask, logits, lens,
                                          out, cnt);
  scan_kernel<<<128 + NLOGW, 64, 0, stream>>>(logits, labels, start_t, end_t,
                                              trans, out, num_den, lens,
                                              segmat, cnt);
}